// Round 13
// baseline (325.568 us; speedup 1.0000x reference)
//
#include <hip/hip_runtime.h>

#define LSEQ 1024

typedef __attribute__((ext_vector_type(8))) short bf16x8;
typedef __attribute__((ext_vector_type(4))) float f32x4;

__device__ __forceinline__ float gelu_f(float x){
    return 0.5f*x*(1.0f+erff(x*0.7071067811865476f));
}

// single-instruction packed f32->bf16 (RTNE, same rounding as bit-twiddle).
__device__ __forceinline__ unsigned cvtpk(float lo, float hi){
    unsigned r;
    asm("v_cvt_pk_bf16_f32 %0, %1, %2" : "=v"(r) : "v"(lo), "v"(hi));
    return r;
}

// ---------------------------------------------------------------------------
// Fused B-panel staging (R13): the old xform kernel's body embedded in gemm
// staging. Builds one 64l x 256k bf16 panel in Bs from the f32 [c][l]
// source: Bs[l][k] = gelu((src[kp+k][n0+l]-mu)*istd*gw+gb [+res]).
// 4 sub-tiles of 64c via T (64x68 f32) transpose scratch; 2 barriers/sub.
// Works because the stats producer is a PRIOR dispatch (atomics complete).
// ---------------------------------------------------------------------------
__device__ __forceinline__ void stage_B_fused(
    short* Bs, float* T,
    const float* __restrict__ src, const float* __restrict__ res,
    const float* __restrict__ gw, const float* __restrict__ gb,
    float mu, float istd, bool has_stats,
    int n0, int kp, int tid)
{
    int cl = tid>>4, l4 = (tid&15)*4;
    int l_loc = tid>>2, cg = (tid&3)*16;
    #pragma unroll
    for(int sub=0; sub<4; sub++){
        int cbase = kp + sub*64;
        float4 tv[4];
        #pragma unroll
        for(int p=0;p<4;p++){
            int c = cbase + p*16 + cl;
            float w_ = 1.f, b_ = 0.f;
            if(has_stats){ w_ = istd; b_ = -mu*istd; }
            if(gw){ b_ = gb[c] + b_*gw[c]; w_ *= gw[c]; }
            float4 v = *(const float4*)&src[(size_t)c*LSEQ + n0 + l4];
            float4 t;
            t.x = v.x*w_+b_; t.y = v.y*w_+b_; t.z = v.z*w_+b_; t.w = v.w*w_+b_;
            if(res){
                float4 rv = *(const float4*)&res[(size_t)c*LSEQ + n0 + l4];
                t.x += rv.x; t.y += rv.y; t.z += rv.z; t.w += rv.w;
            }
            t.x = gelu_f(t.x); t.y = gelu_f(t.y); t.z = gelu_f(t.z); t.w = gelu_f(t.w);
            tv[p] = t;
        }
        __syncthreads();   // prior Bs/T readers done before we overwrite
        #pragma unroll
        for(int p=0;p<4;p++) *(float4*)&T[(p*16+cl)*68 + l4] = tv[p];
        __syncthreads();
        uint4 o0, o1;
        o0.x = cvtpk(T[(cg+0)*68+l_loc],  T[(cg+1)*68+l_loc]);
        o0.y = cvtpk(T[(cg+2)*68+l_loc],  T[(cg+3)*68+l_loc]);
        o0.z = cvtpk(T[(cg+4)*68+l_loc],  T[(cg+5)*68+l_loc]);
        o0.w = cvtpk(T[(cg+6)*68+l_loc],  T[(cg+7)*68+l_loc]);
        o1.x = cvtpk(T[(cg+8)*68+l_loc],  T[(cg+9)*68+l_loc]);
        o1.y = cvtpk(T[(cg+10)*68+l_loc], T[(cg+11)*68+l_loc]);
        o1.z = cvtpk(T[(cg+12)*68+l_loc], T[(cg+13)*68+l_loc]);
        o1.w = cvtpk(T[(cg+14)*68+l_loc], T[(cg+15)*68+l_loc]);
        *(uint4*)&Bs[l_loc*264 + sub*64 + cg]     = o0;
        *(uint4*)&Bs[l_loc*264 + sub*64 + cg + 8] = o1;
    }
    __syncthreads();       // panel ready for MFMA reads
}

// ---------------------------------------------------------------------------
// prologue (R13: xform section removed — gemm_z now stages gelu(f) itself):
// weight pack + stat/cov zeroing only. Grid 547.
// ---------------------------------------------------------------------------
__global__ __launch_bounds__(256,2) void prologue(
    const float* __restrict__ w0, const float* __restrict__ w1,
    const float* __restrict__ w2, const float* __restrict__ w3,
    const float* __restrict__ w4, unsigned short* __restrict__ wdst,
    float* __restrict__ stats, float* __restrict__ covs,
    unsigned* __restrict__ kmaxu)
{
    int b = blockIdx.x;
    int tid = threadIdx.x;

    if(b < 512){
        int idx4 = b*256 + tid;
        const float* src; int off4;
        if(idx4 < 16384){ src=w0; off4=idx4; }
        else if(idx4 < 49152){ src=w1; off4=idx4-16384; }
        else if(idx4 < 65536){ src=w2; off4=idx4-49152; }
        else if(idx4 < 98304){ src=w3; off4=idx4-65536; }
        else { src=w4; off4=idx4-98304; }
        float4 v = ((const float4*)src)[off4];
        uint2 p; p.x = cvtpk(v.x,v.y); p.y = cvtpk(v.z,v.w);
        ((uint2*)wdst)[idx4] = p;
    } else if(b == 512){
        if(tid < 64) ((float4*)stats)[tid] = (float4){0.f,0.f,0.f,0.f};
        if(tid >= 64 && tid < 80) ((uint4*)kmaxu)[tid-64] = (uint4){0,0,0,0};
    } else {
        int i = (b-513)*256 + tid;   // 34 blocks x 256 x f4 = 34816 floats
        ((float4*)covs)[i] = (float4){0.f,0.f,0.f,0.f};
    }
}

// ---------------------------------------------------------------------------
// gemm_fused: C[n] = Abf x gelu(norm(srcF)) with fused B staging. 64x64 tile.
// A direct from global (R7). Stats epilogue: shfl + 2 atomics (R12, R1).
// ---------------------------------------------------------------------------
__global__ __launch_bounds__(256,3) void gemm_fused(
    const unsigned short* __restrict__ Abf,
    const float* __restrict__ srcF, const float* __restrict__ resF,
    const float* __restrict__ in_stats, float cnt_inv, int Csrc,
    const float* __restrict__ gw, const float* __restrict__ gb,
    float* __restrict__ C,
    int M, int K,
    float* __restrict__ out_stats)
{
    __shared__ short Bs[64*264];
    __shared__ float T[64*68];

    int tid = threadIdx.x;
    int n = blockIdx.z, n0 = blockIdx.x*64, m0 = blockIdx.y*64;
    int wave = tid>>6, lane = tid&63;
    int col = lane&15, quad = lane>>4;

    float mu=0.f, istd=1.f;
    bool has_stats = (in_stats != nullptr);
    if(has_stats){
        float s1 = in_stats[2*n], s2 = in_stats[2*n+1];
        mu = s1*cnt_inv;
        istd = rsqrtf(s2*cnt_inv - mu*mu + 1e-5f);
    }
    const float* src = srcF + (size_t)n*Csrc*LSEQ;
    const float* res = resF ? resF + (size_t)n*Csrc*LSEQ : nullptr;

    const unsigned short* apt = Abf + (size_t)(m0+wave*16+col)*K + quad*8;

    f32x4 acc[4];
    #pragma unroll
    for(int t=0;t<4;t++) acc[t] = (f32x4){0.f,0.f,0.f,0.f};

    for(int kp=0; kp<K; kp+=256){
        stage_B_fused(Bs, T, src, res, gw, gb, mu, istd, has_stats, n0, kp, tid);

        #pragma unroll
        for(int kc=0;kc<8;kc++){
            bf16x8 af = *(const bf16x8*)(apt + kp + kc*32);
            #pragma unroll
            for(int t=0;t<4;t++){
                bf16x8 bf = *(bf16x8*)&Bs[(t*16+col)*264 + kc*32 + quad*8];
                acc[t] = __builtin_amdgcn_mfma_f32_16x16x32_bf16(af, bf, acc[t], 0,0,0);
            }
        }
    }

    __syncthreads();
    size_t cbase = (size_t)n*M*LSEQ;
    float lsum=0.f, lsq=0.f;
    #pragma unroll
    for(int t=0;t<4;t++){
        #pragma unroll
        for(int r2=0;r2<4;r2++){
            int m = m0 + wave*16 + quad*4 + r2;
            int l = n0 + t*16 + col;
            float v = acc[t][r2];
            C[cbase + (size_t)m*LSEQ + l] = v;
            lsum += v; lsq += v*v;
        }
    }
    #pragma unroll
    for(int d=1;d<64;d<<=1){
        lsum += __shfl_xor(lsum, d);
        lsq  += __shfl_xor(lsq,  d);
    }
    float* scr = (float*)Bs;
    if(lane==0){ scr[wave] = lsum; scr[8+wave] = lsq; }
    __syncthreads();
    if(tid==0){
        atomicAdd(&out_stats[2*n],   (scr[0]+scr[1])+(scr[2]+scr[3]));
        atomicAdd(&out_stats[2*n+1], (scr[8]+scr[9])+(scr[10]+scr[11]));
    }
}

// ---------------------------------------------------------------------------
// gemm_fused_m128: 128m x 64n tile (R10 WIN structure) with fused B staging.
// ---------------------------------------------------------------------------
__global__ __launch_bounds__(256,3) void gemm_fused_m128(
    const unsigned short* __restrict__ Abf,
    const float* __restrict__ srcF, const float* __restrict__ resF,
    const float* __restrict__ in_stats, float cnt_inv, int Csrc,
    const float* __restrict__ gw, const float* __restrict__ gb,
    float* __restrict__ C,
    int M, int K,
    float* __restrict__ out_stats)
{
    __shared__ short Bs[64*264];
    __shared__ float T[64*68];

    int tid = threadIdx.x;
    int n = blockIdx.z, n0 = blockIdx.x*64, m0 = blockIdx.y*128;
    int wave = tid>>6, lane = tid&63;
    int col = lane&15, quad = lane>>4;

    float mu=0.f, istd=1.f;
    bool has_stats = (in_stats != nullptr);
    if(has_stats){
        float s1 = in_stats[2*n], s2 = in_stats[2*n+1];
        mu = s1*cnt_inv;
        istd = rsqrtf(s2*cnt_inv - mu*mu + 1e-5f);
    }
    const float* src = srcF + (size_t)n*Csrc*LSEQ;
    const float* res = resF ? resF + (size_t)n*Csrc*LSEQ : nullptr;

    const unsigned short* apt0 = Abf + (size_t)(m0+wave*32+col)*K + quad*8;
    const unsigned short* apt1 = apt0 + (size_t)16*K;

    f32x4 acc[2][4];
    #pragma unroll
    for(int mf=0;mf<2;mf++)
        #pragma unroll
        for(int t=0;t<4;t++) acc[mf][t] = (f32x4){0.f,0.f,0.f,0.f};

    for(int kp=0; kp<K; kp+=256){
        stage_B_fused(Bs, T, src, res, gw, gb, mu, istd, has_stats, n0, kp, tid);

        #pragma unroll
        for(int kc=0;kc<8;kc++){
            bf16x8 af0 = *(const bf16x8*)(apt0 + kp + kc*32);
            bf16x8 af1 = *(const bf16x8*)(apt1 + kp + kc*32);
            #pragma unroll
            for(int t=0;t<4;t++){
                bf16x8 bf = *(bf16x8*)&Bs[(t*16+col)*264 + kc*32 + quad*8];
                acc[0][t] = __builtin_amdgcn_mfma_f32_16x16x32_bf16(af0, bf, acc[0][t], 0,0,0);
                acc[1][t] = __builtin_amdgcn_mfma_f32_16x16x32_bf16(af1, bf, acc[1][t], 0,0,0);
            }
        }
    }

    __syncthreads();
    size_t cbase = (size_t)n*M*LSEQ;
    float lsum=0.f, lsq=0.f;
    #pragma unroll
    for(int mf=0;mf<2;mf++){
        #pragma unroll
        for(int t=0;t<4;t++){
            #pragma unroll
            for(int r2=0;r2<4;r2++){
                int m = m0 + wave*32 + mf*16 + quad*4 + r2;
                int l = n0 + t*16 + col;
                float v = acc[mf][t][r2];
                C[cbase + (size_t)m*LSEQ + l] = v;
                lsum += v; lsq += v*v;
            }
        }
    }
    #pragma unroll
    for(int d=1;d<64;d<<=1){
        lsum += __shfl_xor(lsum, d);
        lsq  += __shfl_xor(lsq,  d);
    }
    float* scr = (float*)Bs;
    if(lane==0){ scr[wave] = lsum; scr[8+wave] = lsq; }
    __syncthreads();
    if(tid==0){
        atomicAdd(&out_stats[2*n],   (scr[0]+scr[1])+(scr[2]+scr[3]));
        atomicAdd(&out_stats[2*n+1], (scr[8]+scr[9])+(scr[10]+scr[11]));
    }
}

// ---------------------------------------------------------------------------
// head_cov v2 (unchanged, measured-good): covariances + per-channel sums +
// attn operand pre-pack (Qbf/Kbf/Vbf normalized bf16, qnorm, kmax).
// ---------------------------------------------------------------------------
__global__ __launch_bounds__(256,2) void head_cov(
    const float* __restrict__ qkv,
    const float* __restrict__ s_qkv,
    const float* __restrict__ gq_w, const float* __restrict__ gq_b,
    float* __restrict__ covq, float* __restrict__ covk,
    float* __restrict__ sumq, float* __restrict__ sumk,
    unsigned short* __restrict__ Qbf, unsigned short* __restrict__ Kbf,
    unsigned short* __restrict__ Vbf,
    float* __restrict__ qnorm, unsigned* __restrict__ kmaxu)
{
    __shared__ float Kq[16*132];
    __shared__ float Kk[16*132];
    int b = blockIdx.x;
    int head = b>>3, chunk = b&7;
    int n = head>>3, h = head&7;
    int tid = threadIdx.x;
    int m0 = chunk*128;

    float s1 = s_qkv[2*n], s2v = s_qkv[2*n+1];
    float mu  = s1*(1.f/524288.f);
    float var = s2v*(1.f/524288.f) - mu*mu;
    float istd = rsqrtf(var + 1e-5f);

    const float* base = qkv + (size_t)n*512*LSEQ;
    int m = tid&127, cg = tid>>7;
    #pragma unroll
    for(int cc=0;cc<8;cc++){
        int c = cg*8+cc;
        int chq = h*16+c, chk = 128+h*16+c;
        Kq[c*132+m] = (base[(size_t)chq*LSEQ+m0+m]-mu)*istd*gq_w[chq]+gq_b[chq];
        Kk[c*132+m] = (base[(size_t)chk*LSEQ+m0+m]-mu)*istd*gq_w[chk]+gq_b[chk];
    }

    // ---- V pack (no LDS dependency) ----
    {
        int d = tid>>3, mg = tid&7;
        int ch = 256 + h*32 + d;
        float vw = gq_w[ch]*istd, vb = gq_b[ch]-mu*istd*gq_w[ch];
        const float* vs = base + (size_t)ch*LSEQ + m0 + mg*16;
        float4 a0 = *(const float4*)&vs[0];
        float4 a1 = *(const float4*)&vs[4];
        float4 a2 = *(const float4*)&vs[8];
        float4 a3 = *(const float4*)&vs[12];
        uint4 p0, p1;
        p0.x = cvtpk(a0.x*vw+vb, a0.y*vw+vb);
        p0.y = cvtpk(a0.z*vw+vb, a0.w*vw+vb);
        p0.z = cvtpk(a1.x*vw+vb, a1.y*vw+vb);
        p0.w = cvtpk(a1.z*vw+vb, a1.w*vw+vb);
        p1.x = cvtpk(a2.x*vw+vb, a2.y*vw+vb);
        p1.y = cvtpk(a2.z*vw+vb, a2.w*vw+vb);
        p1.z = cvtpk(a3.x*vw+vb, a3.y*vw+vb);
        p1.w = cvtpk(a3.z*vw+vb, a3.w*vw+vb);
        unsigned short* dv = Vbf + ((size_t)head*32 + d)*1024 + m0 + mg*16;
        *(uint4*)dv = p0;
        *(uint4*)(dv+8) = p1;
    }
    __syncthreads();

    int i = tid>>4, j = tid&15;
    float q0=0,q1=0,q2=0,q3=0, k0=0,k1=0,k2=0,k3=0;
    for(int mm=0;mm<128;mm+=4){
        float4 qa = *(const float4*)&Kq[i*132+mm];
        float4 qb = *(const float4*)&Kq[j*132+mm];
        q0 += qa.x*qb.x; q1 += qa.y*qb.y; q2 += qa.z*qb.z; q3 += qa.w*qb.w;
        float4 ka = *(const float4*)&Kk[i*132+mm];
        float4 kb = *(const float4*)&Kk[j*132+mm];
        k0 += ka.x*kb.x; k1 += ka.y*kb.y; k2 += ka.z*kb.z; k3 += ka.w*kb.w;
    }
    atomicAdd(&covq[head*256 + i*16 + j], (q0+q1)+(q2+q3));
    atomicAdd(&covk[head*256 + i*16 + j], (k0+k1)+(k2+k3));

    if(i==0){
        float s=0.f;
        for(int mm=0;mm<128;mm+=4){
            float4 v = *(const float4*)&Kq[j*132+mm];
            s += (v.x+v.y)+(v.z+v.w);
        }
        atomicAdd(&sumq[head*16+j], s);
    }
    if(i==1){
        float s=0.f;
        for(int mm=0;mm<128;mm+=4){
            float4 v = *(const float4*)&Kk[j*132+mm];
            s += (v.x+v.y)+(v.z+v.w);
        }
        atomicAdd(&sumk[head*16+j], s);
    }

    // ---- Q/K bf16 pack + qnorm + kmax ----
    {
        int mm2 = tid & 127;
        if(tid < 128){
            unsigned u[8]; float s2 = 0.f;
            #pragma unroll
            for(int c=0;c<16;c+=2){
                float a = Kq[c*132+mm2], b2 = Kq[(c+1)*132+mm2];
                s2 += a*a + b2*b2;
                u[c>>1] = cvtpk(a, b2);
            }
            unsigned short* dq = Qbf + ((size_t)head*1024 + m0 + mm2)*16;
            *(uint4*)dq     = *(uint4*)&u[0];
            *(uint4*)(dq+8) = *(uint4*)&u[4];
            qnorm[head*1024 + m0 + mm2] = s2;
        } else {
            unsigned u[8]; float s2 = 0.f;
            #pragma unroll
            for(int c=0;c<16;c+=2){
                float a = Kk[c*132+mm2], b2 = Kk[(c+1)*132+mm2];
                s2 += a*a + b2*b2;
                u[c>>1] = cvtpk(a, b2);
            }
            unsigned short* dk = Kbf + ((size_t)head*1024 + m0 + mm2)*16;
            *(uint4*)dk     = *(uint4*)&u[0];
            *(uint4*)(dk+8) = *(uint4*)&u[4];
            #pragma unroll
            for(int d=1;d<64;d<<=1) s2 = fmaxf(s2, __shfl_xor(s2, d));
            if((tid&63)==0) atomicMax(kmaxu + head, __float_as_uint(s2));
        }
    }
}

// ---------------------------------------------------------------------------
// Attention = R10-exact (passing, 41.2us). exp2f (libm) ONLY.
// QUARANTINE (final): any bare v_exp_f32 path here miscompiles —
// __builtin_amdgcn_exp2f (R6/R9) AND __expf (R11) both fail with identical
// absmax 107.535; libm exp2f passes. Do not retry without isolated probe.
// R8 lesson: occupancy is GRID-bound (512 blocks = 2/CU).
// ---------------------------------------------------------------------------
__global__ __launch_bounds__(256) void attn_kernel(
    const unsigned short* __restrict__ Qbf,
    const unsigned short* __restrict__ Kbf,
    const unsigned short* __restrict__ Vbf,
    const float* __restrict__ qnorm, const unsigned* __restrict__ kmaxu,
    const float* __restrict__ covq, const float* __restrict__ covk,
    const float* __restrict__ sumq, const float* __restrict__ sumk,
    float* __restrict__ out,
    float* __restrict__ out_stats)
{
    __shared__ short Qs[128*40];
    __shared__ short Ks[128*40];
    __shared__ short Vs[32*136];
    __shared__ short Ps[128*152];
    __shared__ float bounds_l[128];
    __shared__ float issum_l[128];
    __shared__ float sred4[4];

    int b = blockIdx.x;
    int head = b&63, rb = b>>6;     // XCD swizzle: all 8 row-blocks of a
    int n = head>>3, h = head&7;    // head share an XCD -> operands L2-hot
    int tid = threadIdx.x;
    int wv = tid>>6, lane = tid&63;
    int col = lane&15, quad = lane>>4;
    int l0 = rb*128;

    // ---- head_fin fold: istd of the LxL logit map ----
    float ih;
    {
        float prod = covq[head*256+tid]*covk[head*256+tid];
        #pragma unroll
        for(int d=1;d<64;d<<=1) prod += __shfl_xor(prod, d);
        if(lane==0) sred4[wv] = prod;
        __syncthreads();
        if(tid==0){
            double S2 = (double)sred4[0] + (double)sred4[1]
                      + (double)sred4[2] + (double)sred4[3];
            double S1 = 0.0;
            for(int c=0;c<16;c++)
                S1 += (double)sumq[head*16+c]*(double)sumk[head*16+c];
            double cnt = 1048576.0;
            double mean = S1/cnt;
            double v2 = S2/cnt - mean*mean;
            if(v2 < 0.0) v2 = 0.0;
            sred4[0] = (float)(1.0/sqrt(v2 + 1e-5));
        }
        __syncthreads();
        ih = sred4[0];
    }
    float ihl = ih * 1.4426950408889634f;   // exp2 path

    // ---- zero MFMA K-pad cols (all 128 rows of Qs AND Ks), stage Q ----
    {
        uint4 z = {0,0,0,0};
        int row = tid>>1, hf = tid&1;                 // row in [0,128)
        *(uint4*)&Ks[row*40 + 16 + hf*8] = z;
        *(uint4*)&Qs[row*40 + 16 + hf*8] = z;
        const unsigned short* qsrc = Qbf + ((size_t)head*1024 + l0 + row)*16 + hf*8;
        *(uint4*)&Qs[row*40 + hf*8] = *(const uint4*)qsrc;
        if(tid < 128) bounds_l[tid] = sqrtf(qnorm[head*1024 + l0 + tid]);
    }
    float kmax = sqrtf(__uint_as_float(kmaxu[head]));
    __syncthreads();

    bf16x8 qf[2];
    float B2l[2]; int grow[2];
    #pragma unroll
    for(int t=0;t<2;t++){
        int rl = (2*wv+t)*16 + col;
        qf[t] = *(bf16x8*)&Qs[rl*40 + quad*8];
        B2l[t] = bounds_l[rl]*kmax*ihl;
        grow[t] = l0 + rl;
    }

    // staging pointers (pure copies from pre-packed bf16)
    int krow = tid>>1, khalf = tid&1;
    const unsigned short* ksrc = Kbf + ((size_t)head*1024 + krow)*16 + khalf*8;
    int vdd = tid>>3, vmg = tid&7;
    const unsigned short* vsrc = Vbf + ((size_t)head*32 + vdd)*1024 + vmg*16;

    f32x4 acc[2][2];
    #pragma unroll
    for(int t=0;t<2;t++){ acc[t][0]=(f32x4){0,0,0,0}; acc[t][1]=(f32x4){0,0,0,0}; }
    float ssum[2] = {0.f,0.f};
    const f32x4 zero4 = {0.f,0.f,0.f,0.f};

    // T14 prefetch of chunk 0
    uint4 kreg = *(const uint4*)ksrc;
    uint4 vr0  = *(const uint4*)vsrc;
    uint4 vr1  = *(const uint4*)(vsrc + 8);

    for(int mc=0;mc<8;mc++){
        int M0 = mc*128;
        *(uint4*)&Ks[krow*40 + khalf*8]    = kreg;
        *(uint4*)&Vs[vdd*136 + vmg*16]     = vr0;
        *(uint4*)&Vs[vdd*136 + vmg*16 + 8] = vr1;
        __syncthreads();

        if(mc < 7){
            kreg = *(const uint4*)(ksrc + (size_t)(M0+128)*16);
            vr0  = *(const uint4*)(vsrc + M0+128);
            vr1  = *(const uint4*)(vsrc + M0+136);
        }

        __builtin_amdgcn_s_setprio(1);
        bool dg = (mc == rb);           // diagonal only in this chunk
        #pragma unroll
        for(int mt=0;mt<8;mt++){
            bf16x8 ak = *(bf16x8*)&Ks[(mt*16+col)*40 + quad*8];
            #pragma unroll
            for(int t=0;t<2;t++){
                f32x4 sc = __builtin_amdgcn_mfma_f32_16x16x32_bf16(ak, qf[t], zero4, 0,0,0);
                float pr[4];
                #pragma unroll
                for(int r=0;r<4;r++)
                    pr[r] = exp2f(fmaf(sc[r], ihl, -B2l[t]));
                if(dg){
                    int mbase = M0 + mt*16 + quad*4;
                    #pragma unroll
                    for(int r=0;r<4;r++)
                        if(mbase + r == grow[t]) pr[r] = 0.f;
                }
                ssum[t] += (pr[0]+pr[1])+(pr[2]+pr[3]);
                uint2 pw;
                pw.x = cvtpk(pr[0],pr[1]); pw.y = cvtpk(pr[2],pr[3]);
                *(uint2*)&Ps[((2*wv+t)*16+col)*152 + mt*16 + quad*4] = pw;
            }
        }
        #pragma unroll
        for(int kk=0;kk<4;kk++){
            bf16x8 bv0 = *(bf16x8*)&Vs[( col)*136 + kk*32 + quad*8];
            bf16x8 bv1 = *(bf16x8*)&Vs[(16+col)*136 + kk*32 + quad*8];
            #pragma unroll
            for(int t=0;t<2;t++){
                bf16x8 ap = *(bf16x8*)&Ps[((2*wv+t)*16+col)*152 + kk*32 + quad*8];
                acc[t][0] = __builtin_amdgcn_mfma_f32_16x16x32_bf16(ap, bv0, acc[t][0], 0,0,0);
                acc[t][1] = __builtin_amdgcn_mfma_f32_16x16x32_bf16(ap, bv1, acc[t][1], 0,0,0);
            }
        }
        __builtin_amdgcn_s_setprio(0);
        __syncthreads();
    }

    #pragma unroll
    for(int t=0;t<2;t++){
        float v = ssum[t];
        v += __shfl_xor(v,16);
        v += __shfl_xor(v,32);
        if(quad==0) issum_l[(2*wv+t)*16+col] = v;
    }
    __syncthreads();
    if(tid<128) issum_l[tid] = 1.f/issum_l[tid];
    __syncthreads();

    float* ep = (float*)Ps;
    #pragma unroll
    for(int t=0;t<2;t++)
        #pragma unroll
        for(int dt=0;dt<2;dt++)
            *(f32x4*)&ep[(dt*16+col)*132 + (2*wv+t)*16 + quad*4] = acc[t][dt];
    __syncthreads();

    float lsum=0.f, lsq=0.f;
    size_t obase = (size_t)n*262144 + (size_t)h*32*LSEQ + l0;
    #pragma unroll
    for(int t=0;t<16;t++){
        int idx = t*256 + tid;
        int d = idx>>7, row = idx&127;
        float y = ep[d*132+row]*issum_l[row];
        out[obase + (size_t)d*LSEQ + row] = y;
        lsum += y; lsq += y*y;
    }
    float* red = (float*)Ks;
    red[tid]=lsum; red[256+tid]=lsq;
    __syncthreads();
    for(int s=128;s>0;s>>=1){
        if(tid<s){ red[tid]+=red[tid+s]; red[256+tid]+=red[256+tid+s]; }
        __syncthreads();
    }
    if(tid==0){
        atomicAdd(&out_stats[2*n],   red[0]);
        atomicAdd(&out_stats[2*n+1], red[256]);
    }
}

// ---------------------------------------------------------------------------
// ew_final: out = gelu( f1 + gn_g2(h2) ), f1 = gelu(f + gn_go(x)) recomputed.
// ---------------------------------------------------------------------------
__global__ __launch_bounds__(256) void ew_final(
    const float* __restrict__ f, const float* __restrict__ x,
    const float* __restrict__ h2,
    const float* __restrict__ sx, const float* __restrict__ sh,
    const float* __restrict__ go_w, const float* __restrict__ go_b,
    const float* __restrict__ g2_w, const float* __restrict__ g2_b,
    float* __restrict__ out)
{
    int idx = blockIdx.x*256 + threadIdx.x;
    int n = idx >> 16;
    int c = (idx >> 8) & 255;
    float mux, isx, muh, ish;
    {
        float s1 = sx[2*n], s2 = sx[2*n+1];
        mux = s1*(1.f/262144.f);
        isx = rsqrtf(s2*(1.f/262144.f) - mux*mux + 1e-5f);
        float t1 = sh[2*n], t2 = sh[2*n+1];
        muh = t1*(1.f/262144.f);
        ish = rsqrtf(t2*(1.f/262144.f) - muh*muh + 1e-5f);
    }
    float wo = go_w[c]*isx, bo = go_b[c]-mux*isx*go_w[c];
    float w2 = g2_w[c]*ish, b2 = g2_b[c]-muh*ish*g2_w[c];
    float4 xv = ((const float4*)x)[idx];
    float4 fv = ((const float4*)f)[idx];
    float4 hv = ((const float4*)h2)[idx];
    float4 ov;
    float f1;
    f1 = gelu_f(fv.x + xv.x*wo+bo); ov.x = gelu_f(f1 + hv.x*w2+b2);
    f1 = gelu_f(fv.y + xv.y*wo+bo); ov.y = gelu_f(f1 + hv.y*w2+b2);
    f1 = gelu_f(fv.z + xv.z*wo+bo); ov.z = gelu_f(f1 + hv.z*w2+b2);
    f1 = gelu_f(fv.w + xv.w*wo+bo); ov.w = gelu_f(f1 + hv.w*w2+b2);
    ((float4*)out)[idx] = ov;
}

// ---------------------------------------------------------------------------
extern "C" void kernel_launch(void* const* d_in, const int* in_sizes, int n_in,
                              void* d_out, int out_size, void* d_ws, size_t ws_size,
                              hipStream_t stream) {
    const float* f     = (const float*)d_in[0];
    const float* w_z   = (const float*)d_in[1];
    const float* gz_w  = (const float*)d_in[2];
    const float* gz_b  = (const float*)d_in[3];
    const float* w_qkv = (const float*)d_in[4];
    const float* gq_w  = (const float*)d_in[5];
    const float* gq_b  = (const float*)d_in[6];
    const float* w_out = (const float*)d_in[7];
    const float* go_w  = (const float*)d_in[8];
    const float* go_b  = (const float*)d_in[9];
    const float* w_f1  = (const float*)d_in[10];
    const float* g1_w  = (const float*)d_in[11];
    const float* g1_b  = (const float*)d_in[12];
    const float* w_f2  = (const float*)d_in[13];
    const float* g2_w  = (const float*)d_in[14];
    const float* g2_b  = (const float*)d_in[15];

    float* ws = (float*)d_ws;
    float* stats = ws;
    float* s_z    = stats + 0;
    float* s_qkv  = stats + 16;
    float* s_attn = stats + 32;
    float* s_x    = stats + 48;
    float* s_h1   = stats + 64;
    float* s_h2   = stats + 80;

    float* qkvF = ws + 256;            // 4M floats: qkv -> h1
    float* z0F  = qkvF + 4194304;      // 2M floats: z0 -> attn_out -> h2
    float* xF   = z0F + 2097152;       // 2M floats: covs/qnorm/kmax -> x
    unsigned short* t0 = (unsigned short*)(xF + 2097152);  // Qbf/Kbf
    unsigned short* t1 = t0 + 2097152;                     // Vbf
    unsigned short* wp = t1 + 2097152;
    unsigned short* wp_z   = wp;
    unsigned short* wp_qkv = wp + 65536;
    unsigned short* wp_out = wp + 196608;
    unsigned short* wp_f1  = wp + 262144;
    unsigned short* wp_f2  = wp + 393216;

    // scratch inside xF (2M floats; only overwritten by gemm w_out AFTER
    // attn has consumed all of these):
    float* covq = xF;                       // 16384
    float* covk = xF + 16384;               // 16384
    float* sumq = xF + 32768;               // 1024
    float* sumk = xF + 33792;               // 1024
    float* qnorm = xF + 34816;              // 65536
    unsigned* kmaxu = (unsigned*)(xF + 100352); // 64

    unsigned short* Qbf = t0;                 // 64*1024*16
    unsigned short* Kbf = t0 + 1048576;       // 64*1024*16
    unsigned short* Vbf = t1;                 // 64*32*1024

    float* outp = (float*)d_out;

    dim3 blk(256);
    // weights pack + zero scratch (xform section gone: gemms stage directly)
    prologue<<<547,blk,0,stream>>>(w_z, w_qkv, w_out, w_f1, w_f2, wp,
        stats, covq, kmaxu);
    // z0 = w_z @ bf16[gelu(f)]                     (fused: no stats)
    gemm_fused<<<dim3(16,4,8),blk,0,stream>>>(wp_z, f, nullptr,
        nullptr, 0.f, 256, nullptr, nullptr, z0F, 256, 256, s_z);
    // qkv = w_qkv @ bf16[gelu(gn_gz(z0))]          (fused: s_z, gz)
    gemm_fused_m128<<<dim3(16,4,8),blk,0,stream>>>(wp_qkv, z0F, nullptr,
        s_z, 1.f/262144.f, 256, gz_w, gz_b, qkvF, 512, 256, s_qkv);
    // per-head covariances + attn operand pre-pack
    head_cov<<<512,blk,0,stream>>>(qkvF, s_qkv, gq_w, gq_b, covq, covk, sumq, sumk,
        Qbf, Kbf, Vbf, qnorm, kmaxu);
    // attention -> attn_out (z0F region)
    attn_kernel<<<512,blk,0,stream>>>(Qbf, Kbf, Vbf, qnorm, kmaxu,
        covq, covk, sumq, sumk, z0F, s_attn);
    // x = w_out @ bf16[gelu(ln(attn_out))]         (fused: s_attn, no gw)
    gemm_fused<<<dim3(16,4,8),blk,0,stream>>>(wp_out, z0F, nullptr,
        s_attn, 1.f/262144.f, 256, nullptr, nullptr, xF, 256, 256, s_x);
    // h1 = w_f1 @ bf16[gelu(f + gn_go(x))]         (fused: s_x, go, res=f)
    gemm_fused_m128<<<dim3(16,4,8),blk,0,stream>>>(wp_f1, xF, f,
        s_x, 1.f/262144.f, 256, go_w, go_b, qkvF, 512, 256, s_h1);
    // h2 = w_f2 @ bf16[gelu(gn_g1(h1))] -> z0F (NOT qkvF: would race with
    // its own B source)                            (fused: s_h1, g1, K=512)
    gemm_fused<<<dim3(16,4,8),blk,0,stream>>>(wp_f2, qkvF, nullptr,
        s_h1, 1.f/524288.f, 512, g1_w, g1_b, z0F, 256, 512, s_h2);
    // out = gelu( gelu(f + gn_go(x)) + gn_g2(h2) )
    ew_final<<<2048,blk,0,stream>>>(f, xF, z0F, s_x, s_h2,
        go_w, go_b, g2_w, g2_b, outp);
}

// Round 14
// 277.939 us; speedup vs baseline: 1.1714x; 1.1714x over previous
//
#include <hip/hip_runtime.h>

#define LSEQ 1024

typedef __attribute__((ext_vector_type(8))) short bf16x8;
typedef __attribute__((ext_vector_type(4))) float f32x4;

__device__ __forceinline__ float gelu_f(float x){
    return 0.5f*x*(1.0f+erff(x*0.7071067811865476f));
}

// single-instruction packed f32->bf16 (RTNE, same rounding as bit-twiddle).
__device__ __forceinline__ unsigned cvtpk(float lo, float hi){
    unsigned r;
    asm("v_cvt_pk_bf16_f32 %0, %1, %2" : "=v"(r) : "v"(lo), "v"(hi));
    return r;
}

// ---------------------------------------------------------------------------
// prologue: one kernel replacing pack_weights + xform_t0 + memsets
// ---------------------------------------------------------------------------
__global__ __launch_bounds__(256,2) void prologue(
    const float* __restrict__ w0, const float* __restrict__ w1,
    const float* __restrict__ w2, const float* __restrict__ w3,
    const float* __restrict__ w4, unsigned short* __restrict__ wdst,
    const float* __restrict__ f, unsigned short* __restrict__ t0,
    float* __restrict__ stats, float* __restrict__ covs,
    unsigned* __restrict__ kmaxu)
{
    __shared__ float T[64][68];
    int b = blockIdx.x;
    int tid = threadIdx.x;

    if(b < 512){
        int ltile = (b&15)*64, ctile = ((b>>4)&3)*64, n = b>>6;
        const float* s = f + (size_t)n*256*LSEQ;
        int cl = tid>>4, l4 = (tid&15)*4;
        #pragma unroll
        for(int p=0;p<4;p++){
            int c_loc = p*16 + cl;
            float4 v = *(const float4*)&s[(size_t)(ctile+c_loc)*LSEQ + ltile + l4];
            float4 t;
            t.x = gelu_f(v.x); t.y = gelu_f(v.y); t.z = gelu_f(v.z); t.w = gelu_f(v.w);
            *(float4*)&T[c_loc][l4] = t;
        }
        __syncthreads();
        int l_loc = tid>>2, cg = (tid&3)*16;
        uint4 o0, o1;
        o0.x = cvtpk(T[cg+0][l_loc],  T[cg+1][l_loc]);
        o0.y = cvtpk(T[cg+2][l_loc],  T[cg+3][l_loc]);
        o0.z = cvtpk(T[cg+4][l_loc],  T[cg+5][l_loc]);
        o0.w = cvtpk(T[cg+6][l_loc],  T[cg+7][l_loc]);
        o1.x = cvtpk(T[cg+8][l_loc],  T[cg+9][l_loc]);
        o1.y = cvtpk(T[cg+10][l_loc], T[cg+11][l_loc]);
        o1.z = cvtpk(T[cg+12][l_loc], T[cg+13][l_loc]);
        o1.w = cvtpk(T[cg+14][l_loc], T[cg+15][l_loc]);
        unsigned short* d = t0 + (size_t)n*LSEQ*256 + (size_t)(ltile+l_loc)*256 + ctile + cg;
        *(uint4*)d = o0;
        *(uint4*)(d+8) = o1;
    } else if(b < 1024){
        int idx4 = (b-512)*256 + tid;
        const float* src; int off4;
        if(idx4 < 16384){ src=w0; off4=idx4; }
        else if(idx4 < 49152){ src=w1; off4=idx4-16384; }
        else if(idx4 < 65536){ src=w2; off4=idx4-49152; }
        else if(idx4 < 98304){ src=w3; off4=idx4-65536; }
        else { src=w4; off4=idx4-98304; }
        float4 v = ((const float4*)src)[off4];
        uint2 p; p.x = cvtpk(v.x,v.y); p.y = cvtpk(v.z,v.w);
        ((uint2*)wdst)[idx4] = p;
    } else if(b == 1024){
        if(tid < 64) ((float4*)stats)[tid] = (float4){0.f,0.f,0.f,0.f};
        if(tid >= 64 && tid < 80) ((uint4*)kmaxu)[tid-64] = (uint4){0,0,0,0};
    } else {
        int i = (b-1025)*256 + tid;
        ((float4*)covs)[i] = (float4){0.f,0.f,0.f,0.f};
    }
}

// ---------------------------------------------------------------------------
// xform_bf16: dst[l][c] (bf16, l-major) = gelu( (src[c][l]-mu)*istd*gw+gb
//                                               [+ res[c][l]] )
// R13 lesson: do NOT fuse this into the consuming gemm — each of the 4
// m-blocks sharing a B-panel would redo it (4x staging work, MfmaUtil 1.5%,
// +45us). Standalone runs it exactly once per element.
// ---------------------------------------------------------------------------
__global__ __launch_bounds__(256,2) void xform_bf16(
    const float* __restrict__ src, const float* __restrict__ res,
    const float* __restrict__ stats,
    const float* __restrict__ gw, const float* __restrict__ gb,
    float cnt_inv, int C, unsigned short* __restrict__ dst)
{
    __shared__ float T[64][68];
    int n = blockIdx.z;
    int ltile = blockIdx.x*64, ctile = blockIdx.y*64;
    int tid = threadIdx.x;

    float mu=0.f, istd=1.f;
    if(stats){
        float s1 = stats[2*n], s2 = stats[2*n+1];
        mu = s1*cnt_inv;
        istd = rsqrtf(s2*cnt_inv - mu*mu + 1e-5f);
    }
    const float* s = src + (size_t)n*C*LSEQ;
    const float* r = res ? res + (size_t)n*C*LSEQ : nullptr;

    int cl = tid>>4, l4 = (tid&15)*4;
    #pragma unroll
    for(int p=0;p<4;p++){
        int c_loc = p*16 + cl;
        int c = ctile + c_loc;
        float w_ = 1.f, b_ = 0.f;
        if(stats){ w_ = istd; b_ = -mu*istd; }
        if(gw){ b_ = gb[c] + b_*gw[c]; w_ *= gw[c]; }
        float4 v = *(const float4*)&s[(size_t)c*LSEQ + ltile + l4];
        float4 t;
        t.x = v.x*w_+b_; t.y = v.y*w_+b_; t.z = v.z*w_+b_; t.w = v.w*w_+b_;
        if(r){
            float4 rv = *(const float4*)&r[(size_t)c*LSEQ + ltile + l4];
            t.x += rv.x; t.y += rv.y; t.z += rv.z; t.w += rv.w;
        }
        t.x = gelu_f(t.x); t.y = gelu_f(t.y); t.z = gelu_f(t.z); t.w = gelu_f(t.w);
        *(float4*)&T[c_loc][l4] = t;
    }
    __syncthreads();

    int l_loc = tid>>2, cg = (tid&3)*16;
    uint4 o0, o1;
    o0.x = cvtpk(T[cg+0][l_loc],  T[cg+1][l_loc]);
    o0.y = cvtpk(T[cg+2][l_loc],  T[cg+3][l_loc]);
    o0.z = cvtpk(T[cg+4][l_loc],  T[cg+5][l_loc]);
    o0.w = cvtpk(T[cg+6][l_loc],  T[cg+7][l_loc]);
    o1.x = cvtpk(T[cg+8][l_loc],  T[cg+9][l_loc]);
    o1.y = cvtpk(T[cg+10][l_loc], T[cg+11][l_loc]);
    o1.z = cvtpk(T[cg+12][l_loc], T[cg+13][l_loc]);
    o1.w = cvtpk(T[cg+14][l_loc], T[cg+15][l_loc]);
    unsigned short* d = dst + (size_t)n*LSEQ*C + (size_t)(ltile+l_loc)*C + ctile + cg;
    *(uint4*)d = o0;
    *(uint4*)(d+8) = o1;
}

// ---------------------------------------------------------------------------
// gemm_bf16 v3: A direct from global (R7: no cross-wave reuse, LDS staging
// of A was pure overhead), B LDS-staged (4x wave reuse). 64x64 tile.
// Stats epilogue: wave shfl reduce + 2 atomics/block via tid==0 (R12;
// R1 lesson: never fan out atomics per-wave to one hot line).
// ---------------------------------------------------------------------------
__global__ __launch_bounds__(256,4) void gemm_bf16(
    const unsigned short* __restrict__ Abf,
    const unsigned short* __restrict__ Bbf,
    float* __restrict__ C,
    int M, int K,
    float* __restrict__ out_stats)
{
    __shared__ short Bs[64*264];

    int tid = threadIdx.x;
    int n = blockIdx.z, n0 = blockIdx.x*64, m0 = blockIdx.y*64;
    int wave = tid>>6, lane = tid&63;
    int col = lane&15, quad = lane>>4;
    int srow = tid>>2, sks = (tid&3)*8;

    const unsigned short* apt = Abf + (size_t)(m0+wave*16+col)*K + quad*8;
    const unsigned short* bpt = Bbf + ((size_t)n*LSEQ + n0+srow)*K + sks;

    f32x4 acc[4];
    #pragma unroll
    for(int t=0;t<4;t++) acc[t] = (f32x4){0.f,0.f,0.f,0.f};

    for(int kp=0; kp<K; kp+=256){
        __syncthreads();
        uint4 bw[8];
        #pragma unroll
        for(int i=0;i<8;i++) bw[i] = *(const uint4*)(bpt + kp + i*32);
        #pragma unroll
        for(int i=0;i<8;i++) *(uint4*)&Bs[srow*264 + sks + i*32] = bw[i];
        __syncthreads();

        #pragma unroll
        for(int kc=0;kc<8;kc++){
            bf16x8 af = *(const bf16x8*)(apt + kp + kc*32);
            #pragma unroll
            for(int t=0;t<4;t++){
                bf16x8 bf = *(bf16x8*)&Bs[(t*16+col)*264 + kc*32 + quad*8];
                acc[t] = __builtin_amdgcn_mfma_f32_16x16x32_bf16(af, bf, acc[t], 0,0,0);
            }
        }
    }

    __syncthreads();
    size_t cbase = (size_t)n*M*LSEQ;
    float lsum=0.f, lsq=0.f;
    #pragma unroll
    for(int t=0;t<4;t++){
        #pragma unroll
        for(int r2=0;r2<4;r2++){
            int m = m0 + wave*16 + quad*4 + r2;
            int l = n0 + t*16 + col;
            float v = acc[t][r2];
            C[cbase + (size_t)m*LSEQ + l] = v;
            lsum += v; lsq += v*v;
        }
    }
    #pragma unroll
    for(int d=1;d<64;d<<=1){
        lsum += __shfl_xor(lsum, d);
        lsq  += __shfl_xor(lsq,  d);
    }
    float* scr = (float*)Bs;
    if(lane==0){ scr[wave] = lsum; scr[8+wave] = lsq; }
    __syncthreads();
    if(tid==0){
        atomicAdd(&out_stats[2*n],   (scr[0]+scr[1])+(scr[2]+scr[3]));
        atomicAdd(&out_stats[2*n+1], (scr[8]+scr[9])+(scr[10]+scr[11]));
    }
}

// ---------------------------------------------------------------------------
// gemm_bf16_m128 (R10, WIN: pipeline -24us): 128m x 64n tile for the M=512
// gemms. Each wave owns 2 m-frags: 64 MFMA per staged B-panel, 2x bf
// LDS-read reuse, half the redundant B staging.
// ---------------------------------------------------------------------------
__global__ __launch_bounds__(256,4) void gemm_bf16_m128(
    const unsigned short* __restrict__ Abf,
    const unsigned short* __restrict__ Bbf,
    float* __restrict__ C,
    int M, int K,
    float* __restrict__ out_stats)
{
    __shared__ short Bs[64*264];

    int tid = threadIdx.x;
    int n = blockIdx.z, n0 = blockIdx.x*64, m0 = blockIdx.y*128;
    int wave = tid>>6, lane = tid&63;
    int col = lane&15, quad = lane>>4;
    int srow = tid>>2, sks = (tid&3)*8;

    const unsigned short* apt0 = Abf + (size_t)(m0+wave*32+col)*K + quad*8;
    const unsigned short* apt1 = apt0 + (size_t)16*K;
    const unsigned short* bpt = Bbf + ((size_t)n*LSEQ + n0+srow)*K + sks;

    f32x4 acc[2][4];
    #pragma unroll
    for(int mf=0;mf<2;mf++)
        #pragma unroll
        for(int t=0;t<4;t++) acc[mf][t] = (f32x4){0.f,0.f,0.f,0.f};

    for(int kp=0; kp<K; kp+=256){
        __syncthreads();
        uint4 bw[8];
        #pragma unroll
        for(int i=0;i<8;i++) bw[i] = *(const uint4*)(bpt + kp + i*32);
        #pragma unroll
        for(int i=0;i<8;i++) *(uint4*)&Bs[srow*264 + sks + i*32] = bw[i];
        __syncthreads();

        #pragma unroll
        for(int kc=0;kc<8;kc++){
            bf16x8 af0 = *(const bf16x8*)(apt0 + kp + kc*32);
            bf16x8 af1 = *(const bf16x8*)(apt1 + kp + kc*32);
            #pragma unroll
            for(int t=0;t<4;t++){
                bf16x8 bf = *(bf16x8*)&Bs[(t*16+col)*264 + kc*32 + quad*8];
                acc[0][t] = __builtin_amdgcn_mfma_f32_16x16x32_bf16(af0, bf, acc[0][t], 0,0,0);
                acc[1][t] = __builtin_amdgcn_mfma_f32_16x16x32_bf16(af1, bf, acc[1][t], 0,0,0);
            }
        }
    }

    __syncthreads();
    size_t cbase = (size_t)n*M*LSEQ;
    float lsum=0.f, lsq=0.f;
    #pragma unroll
    for(int mf=0;mf<2;mf++){
        #pragma unroll
        for(int t=0;t<4;t++){
            #pragma unroll
            for(int r2=0;r2<4;r2++){
                int m = m0 + wave*32 + mf*16 + quad*4 + r2;
                int l = n0 + t*16 + col;
                float v = acc[mf][t][r2];
                C[cbase + (size_t)m*LSEQ + l] = v;
                lsum += v; lsq += v*v;
            }
        }
    }
    #pragma unroll
    for(int d=1;d<64;d<<=1){
        lsum += __shfl_xor(lsum, d);
        lsq  += __shfl_xor(lsq,  d);
    }
    float* scr = (float*)Bs;
    if(lane==0){ scr[wave] = lsum; scr[8+wave] = lsq; }
    __syncthreads();
    if(tid==0){
        atomicAdd(&out_stats[2*n],   (scr[0]+scr[1])+(scr[2]+scr[3]));
        atomicAdd(&out_stats[2*n+1], (scr[8]+scr[9])+(scr[10]+scr[11]));
    }
}

// ---------------------------------------------------------------------------
// head_cov v2 (unchanged, measured-good): covariances + per-channel sums +
// attn operand pre-pack (Qbf/Kbf/Vbf normalized bf16, qnorm, kmax).
// ---------------------------------------------------------------------------
__global__ __launch_bounds__(256,2) void head_cov(
    const float* __restrict__ qkv,
    const float* __restrict__ s_qkv,
    const float* __restrict__ gq_w, const float* __restrict__ gq_b,
    float* __restrict__ covq, float* __restrict__ covk,
    float* __restrict__ sumq, float* __restrict__ sumk,
    unsigned short* __restrict__ Qbf, unsigned short* __restrict__ Kbf,
    unsigned short* __restrict__ Vbf,
    float* __restrict__ qnorm, unsigned* __restrict__ kmaxu)
{
    __shared__ float Kq[16*132];
    __shared__ float Kk[16*132];
    int b = blockIdx.x;
    int head = b>>3, chunk = b&7;
    int n = head>>3, h = head&7;
    int tid = threadIdx.x;
    int m0 = chunk*128;

    float s1 = s_qkv[2*n], s2v = s_qkv[2*n+1];
    float mu  = s1*(1.f/524288.f);
    float var = s2v*(1.f/524288.f) - mu*mu;
    float istd = rsqrtf(var + 1e-5f);

    const float* base = qkv + (size_t)n*512*LSEQ;
    int m = tid&127, cg = tid>>7;
    #pragma unroll
    for(int cc=0;cc<8;cc++){
        int c = cg*8+cc;
        int chq = h*16+c, chk = 128+h*16+c;
        Kq[c*132+m] = (base[(size_t)chq*LSEQ+m0+m]-mu)*istd*gq_w[chq]+gq_b[chq];
        Kk[c*132+m] = (base[(size_t)chk*LSEQ+m0+m]-mu)*istd*gq_w[chk]+gq_b[chk];
    }

    // ---- V pack (no LDS dependency) ----
    {
        int d = tid>>3, mg = tid&7;
        int ch = 256 + h*32 + d;
        float vw = gq_w[ch]*istd, vb = gq_b[ch]-mu*istd*gq_w[ch];
        const float* vs = base + (size_t)ch*LSEQ + m0 + mg*16;
        float4 a0 = *(const float4*)&vs[0];
        float4 a1 = *(const float4*)&vs[4];
        float4 a2 = *(const float4*)&vs[8];
        float4 a3 = *(const float4*)&vs[12];
        uint4 p0, p1;
        p0.x = cvtpk(a0.x*vw+vb, a0.y*vw+vb);
        p0.y = cvtpk(a0.z*vw+vb, a0.w*vw+vb);
        p0.z = cvtpk(a1.x*vw+vb, a1.y*vw+vb);
        p0.w = cvtpk(a1.z*vw+vb, a1.w*vw+vb);
        p1.x = cvtpk(a2.x*vw+vb, a2.y*vw+vb);
        p1.y = cvtpk(a2.z*vw+vb, a2.w*vw+vb);
        p1.z = cvtpk(a3.x*vw+vb, a3.y*vw+vb);
        p1.w = cvtpk(a3.z*vw+vb, a3.w*vw+vb);
        unsigned short* dv = Vbf + ((size_t)head*32 + d)*1024 + m0 + mg*16;
        *(uint4*)dv = p0;
        *(uint4*)(dv+8) = p1;
    }
    __syncthreads();

    int i = tid>>4, j = tid&15;
    float q0=0,q1=0,q2=0,q3=0, k0=0,k1=0,k2=0,k3=0;
    for(int mm=0;mm<128;mm+=4){
        float4 qa = *(const float4*)&Kq[i*132+mm];
        float4 qb = *(const float4*)&Kq[j*132+mm];
        q0 += qa.x*qb.x; q1 += qa.y*qb.y; q2 += qa.z*qb.z; q3 += qa.w*qb.w;
        float4 ka = *(const float4*)&Kk[i*132+mm];
        float4 kb = *(const float4*)&Kk[j*132+mm];
        k0 += ka.x*kb.x; k1 += ka.y*kb.y; k2 += ka.z*kb.z; k3 += ka.w*kb.w;
    }
    atomicAdd(&covq[head*256 + i*16 + j], (q0+q1)+(q2+q3));
    atomicAdd(&covk[head*256 + i*16 + j], (k0+k1)+(k2+k3));

    if(i==0){
        float s=0.f;
        for(int mm=0;mm<128;mm+=4){
            float4 v = *(const float4*)&Kq[j*132+mm];
            s += (v.x+v.y)+(v.z+v.w);
        }
        atomicAdd(&sumq[head*16+j], s);
    }
    if(i==1){
        float s=0.f;
        for(int mm=0;mm<128;mm+=4){
            float4 v = *(const float4*)&Kk[j*132+mm];
            s += (v.x+v.y)+(v.z+v.w);
        }
        atomicAdd(&sumk[head*16+j], s);
    }

    // ---- Q/K bf16 pack + qnorm + kmax ----
    {
        int mm2 = tid & 127;
        if(tid < 128){
            unsigned u[8]; float s2 = 0.f;
            #pragma unroll
            for(int c=0;c<16;c+=2){
                float a = Kq[c*132+mm2], b2 = Kq[(c+1)*132+mm2];
                s2 += a*a + b2*b2;
                u[c>>1] = cvtpk(a, b2);
            }
            unsigned short* dq = Qbf + ((size_t)head*1024 + m0 + mm2)*16;
            *(uint4*)dq     = *(uint4*)&u[0];
            *(uint4*)(dq+8) = *(uint4*)&u[4];
            qnorm[head*1024 + m0 + mm2] = s2;
        } else {
            unsigned u[8]; float s2 = 0.f;
            #pragma unroll
            for(int c=0;c<16;c+=2){
                float a = Kk[c*132+mm2], b2 = Kk[(c+1)*132+mm2];
                s2 += a*a + b2*b2;
                u[c>>1] = cvtpk(a, b2);
            }
            unsigned short* dk = Kbf + ((size_t)head*1024 + m0 + mm2)*16;
            *(uint4*)dk     = *(uint4*)&u[0];
            *(uint4*)(dk+8) = *(uint4*)&u[4];
            #pragma unroll
            for(int d=1;d<64;d<<=1) s2 = fmaxf(s2, __shfl_xor(s2, d));
            if((tid&63)==0) atomicMax(kmaxu + head, __float_as_uint(s2));
        }
    }
}

// ---------------------------------------------------------------------------
// Attention = R10-exact (passing, 41.2us). exp2f (libm) ONLY.
// QUARANTINE (final): any bare v_exp_f32 path here miscompiles —
// __builtin_amdgcn_exp2f (R6/R9) AND __expf (R11) both fail with identical
// absmax 107.535; libm exp2f passes. Do not retry without isolated probe.
// R8 lesson: occupancy is GRID-bound (512 blocks = 2/CU).
// ---------------------------------------------------------------------------
__global__ __launch_bounds__(256) void attn_kernel(
    const unsigned short* __restrict__ Qbf,
    const unsigned short* __restrict__ Kbf,
    const unsigned short* __restrict__ Vbf,
    const float* __restrict__ qnorm, const unsigned* __restrict__ kmaxu,
    const float* __restrict__ covq, const float* __restrict__ covk,
    const float* __restrict__ sumq, const float* __restrict__ sumk,
    float* __restrict__ out,
    float* __restrict__ out_stats)
{
    __shared__ short Qs[128*40];
    __shared__ short Ks[128*40];
    __shared__ short Vs[32*136];
    __shared__ short Ps[128*152];
    __shared__ float bounds_l[128];
    __shared__ float issum_l[128];
    __shared__ float sred4[4];

    int b = blockIdx.x;
    int head = b&63, rb = b>>6;     // XCD swizzle: all 8 row-blocks of a
    int n = head>>3, h = head&7;    // head share an XCD -> operands L2-hot
    int tid = threadIdx.x;
    int wv = tid>>6, lane = tid&63;
    int col = lane&15, quad = lane>>4;
    int l0 = rb*128;

    // ---- head_fin fold: istd of the LxL logit map ----
    float ih;
    {
        float prod = covq[head*256+tid]*covk[head*256+tid];
        #pragma unroll
        for(int d=1;d<64;d<<=1) prod += __shfl_xor(prod, d);
        if(lane==0) sred4[wv] = prod;
        __syncthreads();
        if(tid==0){
            double S2 = (double)sred4[0] + (double)sred4[1]
                      + (double)sred4[2] + (double)sred4[3];
            double S1 = 0.0;
            for(int c=0;c<16;c++)
                S1 += (double)sumq[head*16+c]*(double)sumk[head*16+c];
            double cnt = 1048576.0;
            double mean = S1/cnt;
            double v2 = S2/cnt - mean*mean;
            if(v2 < 0.0) v2 = 0.0;
            sred4[0] = (float)(1.0/sqrt(v2 + 1e-5));
        }
        __syncthreads();
        ih = sred4[0];
    }
    float ihl = ih * 1.4426950408889634f;   // exp2 path

    // ---- zero MFMA K-pad cols (all 128 rows of Qs AND Ks), stage Q ----
    {
        uint4 z = {0,0,0,0};
        int row = tid>>1, hf = tid&1;                 // row in [0,128)
        *(uint4*)&Ks[row*40 + 16 + hf*8] = z;
        *(uint4*)&Qs[row*40 + 16 + hf*8] = z;
        const unsigned short* qsrc = Qbf + ((size_t)head*1024 + l0 + row)*16 + hf*8;
        *(uint4*)&Qs[row*40 + hf*8] = *(const uint4*)qsrc;
        if(tid < 128) bounds_l[tid] = sqrtf(qnorm[head*1024 + l0 + tid]);
    }
    float kmax = sqrtf(__uint_as_float(kmaxu[head]));
    __syncthreads();

    bf16x8 qf[2];
    float B2l[2]; int grow[2];
    #pragma unroll
    for(int t=0;t<2;t++){
        int rl = (2*wv+t)*16 + col;
        qf[t] = *(bf16x8*)&Qs[rl*40 + quad*8];
        B2l[t] = bounds_l[rl]*kmax*ihl;
        grow[t] = l0 + rl;
    }

    // staging pointers (pure copies from pre-packed bf16)
    int krow = tid>>1, khalf = tid&1;
    const unsigned short* ksrc = Kbf + ((size_t)head*1024 + krow)*16 + khalf*8;
    int vdd = tid>>3, vmg = tid&7;
    const unsigned short* vsrc = Vbf + ((size_t)head*32 + vdd)*1024 + vmg*16;

    f32x4 acc[2][2];
    #pragma unroll
    for(int t=0;t<2;t++){ acc[t][0]=(f32x4){0,0,0,0}; acc[t][1]=(f32x4){0,0,0,0}; }
    float ssum[2] = {0.f,0.f};
    const f32x4 zero4 = {0.f,0.f,0.f,0.f};

    // T14 prefetch of chunk 0
    uint4 kreg = *(const uint4*)ksrc;
    uint4 vr0  = *(const uint4*)vsrc;
    uint4 vr1  = *(const uint4*)(vsrc + 8);

    for(int mc=0;mc<8;mc++){
        int M0 = mc*128;
        *(uint4*)&Ks[krow*40 + khalf*8]    = kreg;
        *(uint4*)&Vs[vdd*136 + vmg*16]     = vr0;
        *(uint4*)&Vs[vdd*136 + vmg*16 + 8] = vr1;
        __syncthreads();

        if(mc < 7){
            kreg = *(const uint4*)(ksrc + (size_t)(M0+128)*16);
            vr0  = *(const uint4*)(vsrc + M0+128);
            vr1  = *(const uint4*)(vsrc + M0+136);
        }

        __builtin_amdgcn_s_setprio(1);
        bool dg = (mc == rb);           // diagonal only in this chunk
        #pragma unroll
        for(int mt=0;mt<8;mt++){
            bf16x8 ak = *(bf16x8*)&Ks[(mt*16+col)*40 + quad*8];
            #pragma unroll
            for(int t=0;t<2;t++){
                f32x4 sc = __builtin_amdgcn_mfma_f32_16x16x32_bf16(ak, qf[t], zero4, 0,0,0);
                float pr[4];
                #pragma unroll
                for(int r=0;r<4;r++)
                    pr[r] = exp2f(fmaf(sc[r], ihl, -B2l[t]));
                if(dg){
                    int mbase = M0 + mt*16 + quad*4;
                    #pragma unroll
                    for(int r=0;r<4;r++)
                        if(mbase + r == grow[t]) pr[r] = 0.f;
                }
                ssum[t] += (pr[0]+pr[1])+(pr[2]+pr[3]);
                uint2 pw;
                pw.x = cvtpk(pr[0],pr[1]); pw.y = cvtpk(pr[2],pr[3]);
                *(uint2*)&Ps[((2*wv+t)*16+col)*152 + mt*16 + quad*4] = pw;
            }
        }
        #pragma unroll
        for(int kk=0;kk<4;kk++){
            bf16x8 bv0 = *(bf16x8*)&Vs[( col)*136 + kk*32 + quad*8];
            bf16x8 bv1 = *(bf16x8*)&Vs[(16+col)*136 + kk*32 + quad*8];
            #pragma unroll
            for(int t=0;t<2;t++){
                bf16x8 ap = *(bf16x8*)&Ps[((2*wv+t)*16+col)*152 + kk*32 + quad*8];
                acc[t][0] = __builtin_amdgcn_mfma_f32_16x16x32_bf16(ap, bv0, acc[t][0], 0,0,0);
                acc[t][1] = __builtin_amdgcn_mfma_f32_16x16x32_bf16(ap, bv1, acc[t][1], 0,0,0);
            }
        }
        __builtin_amdgcn_s_setprio(0);
        __syncthreads();
    }

    #pragma unroll
    for(int t=0;t<2;t++){
        float v = ssum[t];
        v += __shfl_xor(v,16);
        v += __shfl_xor(v,32);
        if(quad==0) issum_l[(2*wv+t)*16+col] = v;
    }
    __syncthreads();
    if(tid<128) issum_l[tid] = 1.f/issum_l[tid];
    __syncthreads();

    float* ep = (float*)Ps;
    #pragma unroll
    for(int t=0;t<2;t++)
        #pragma unroll
        for(int dt=0;dt<2;dt++)
            *(f32x4*)&ep[(dt*16+col)*132 + (2*wv+t)*16 + quad*4] = acc[t][dt];
    __syncthreads();

    float lsum=0.f, lsq=0.f;
    size_t obase = (size_t)n*262144 + (size_t)h*32*LSEQ + l0;
    #pragma unroll
    for(int t=0;t<16;t++){
        int idx = t*256 + tid;
        int d = idx>>7, row = idx&127;
        float y = ep[d*132+row]*issum_l[row];
        out[obase + (size_t)d*LSEQ + row] = y;
        lsum += y; lsq += y*y;
    }
    float* red = (float*)Ks;
    red[tid]=lsum; red[256+tid]=lsq;
    __syncthreads();
    for(int s=128;s>0;s>>=1){
        if(tid<s){ red[tid]+=red[tid+s]; red[256+tid]+=red[256+tid+s]; }
        __syncthreads();
    }
    if(tid==0){
        atomicAdd(&out_stats[2*n],   red[0]);
        atomicAdd(&out_stats[2*n+1], red[256]);
    }
}

// ---------------------------------------------------------------------------
// ew_final: out = gelu( f1 + gn_g2(h2) ), f1 = gelu(f + gn_go(x)) recomputed.
// ---------------------------------------------------------------------------
__global__ __launch_bounds__(256) void ew_final(
    const float* __restrict__ f, const float* __restrict__ x,
    const float* __restrict__ h2,
    const float* __restrict__ sx, const float* __restrict__ sh,
    const float* __restrict__ go_w, const float* __restrict__ go_b,
    const float* __restrict__ g2_w, const float* __restrict__ g2_b,
    float* __restrict__ out)
{
    int idx = blockIdx.x*256 + threadIdx.x;
    int n = idx >> 16;
    int c = (idx >> 8) & 255;
    float mux, isx, muh, ish;
    {
        float s1 = sx[2*n], s2 = sx[2*n+1];
        mux = s1*(1.f/262144.f);
        isx = rsqrtf(s2*(1.f/262144.f) - mux*mux + 1e-5f);
        float t1 = sh[2*n], t2 = sh[2*n+1];
        muh = t1*(1.f/262144.f);
        ish = rsqrtf(t2*(1.f/262144.f) - muh*muh + 1e-5f);
    }
    float wo = go_w[c]*isx, bo = go_b[c]-mux*isx*go_w[c];
    float w2 = g2_w[c]*ish, b2 = g2_b[c]-muh*ish*g2_w[c];
    float4 xv = ((const float4*)x)[idx];
    float4 fv = ((const float4*)f)[idx];
    float4 hv = ((const float4*)h2)[idx];
    float4 ov;
    float f1;
    f1 = gelu_f(fv.x + xv.x*wo+bo); ov.x = gelu_f(f1 + hv.x*w2+b2);
    f1 = gelu_f(fv.y + xv.y*wo+bo); ov.y = gelu_f(f1 + hv.y*w2+b2);
    f1 = gelu_f(fv.z + xv.z*wo+bo); ov.z = gelu_f(f1 + hv.z*w2+b2);
    f1 = gelu_f(fv.w + xv.w*wo+bo); ov.w = gelu_f(f1 + hv.w*w2+b2);
    ((float4*)out)[idx] = ov;
}

// ---------------------------------------------------------------------------
extern "C" void kernel_launch(void* const* d_in, const int* in_sizes, int n_in,
                              void* d_out, int out_size, void* d_ws, size_t ws_size,
                              hipStream_t stream) {
    const float* f     = (const float*)d_in[0];
    const float* w_z   = (const float*)d_in[1];
    const float* gz_w  = (const float*)d_in[2];
    const float* gz_b  = (const float*)d_in[3];
    const float* w_qkv = (const float*)d_in[4];
    const float* gq_w  = (const float*)d_in[5];
    const float* gq_b  = (const float*)d_in[6];
    const float* w_out = (const float*)d_in[7];
    const float* go_w  = (const float*)d_in[8];
    const float* go_b  = (const float*)d_in[9];
    const float* w_f1  = (const float*)d_in[10];
    const float* g1_w  = (const float*)d_in[11];
    const float* g1_b  = (const float*)d_in[12];
    const float* w_f2  = (const float*)d_in[13];
    const float* g2_w  = (const float*)d_in[14];
    const float* g2_b  = (const float*)d_in[15];

    float* ws = (float*)d_ws;
    float* stats = ws;
    float* s_z    = stats + 0;
    float* s_qkv  = stats + 16;
    float* s_attn = stats + 32;
    float* s_x    = stats + 48;
    float* s_h1   = stats + 64;
    float* s_h2   = stats + 80;

    float* qkvF = ws + 256;            // 4M floats: qkv -> h1 -> h2
    float* z0F  = qkvF + 4194304;      // 2M floats: z0 -> attn_out -> t4(bf16)
    float* xF   = z0F + 2097152;       // 2M floats: covs/qnorm/kmax -> x
    unsigned short* t0 = (unsigned short*)(xF + 2097152);  // t0 -> Qbf/Kbf -> t2
    unsigned short* t1 = t0 + 2097152;                     // t1 -> Vbf -> t3
    unsigned short* wp = t1 + 2097152;
    unsigned short* t4 = (unsigned short*)z0F;
    unsigned short* wp_z   = wp;
    unsigned short* wp_qkv = wp + 65536;
    unsigned short* wp_out = wp + 196608;
    unsigned short* wp_f1  = wp + 262144;
    unsigned short* wp_f2  = wp + 393216;

    // scratch inside xF (2M floats; only overwritten by gemm w_out AFTER
    // attn has consumed all of these):
    float* covq = xF;                       // 16384
    float* covk = xF + 16384;               // 16384
    float* sumq = xF + 32768;               // 1024
    float* sumk = xF + 33792;               // 1024
    float* qnorm = xF + 34816;              // 65536
    unsigned* kmaxu = (unsigned*)(xF + 100352); // 64

    // attn pre-packed operands alias the dead t0/t1 regions:
    // t0 dead after gemm z; reused as t2 only after attn.
    // t1 dead after gemm qkv; reused as t3 only after attn.
    unsigned short* Qbf = t0;                 // 64*1024*16
    unsigned short* Kbf = t0 + 1048576;       // 64*1024*16
    unsigned short* Vbf = t1;                 // 64*32*1024

    float* outp = (float*)d_out;

    dim3 blk(256);
    prologue<<<1059,blk,0,stream>>>(w_z, w_qkv, w_out, w_f1, w_f2, wp,
        f, t0, stats, covq, kmaxu);
    gemm_bf16<<<dim3(16,4,8),blk,0,stream>>>(wp_z, t0, z0F, 256, 256, s_z);
    xform_bf16<<<dim3(16,4,8),blk,0,stream>>>(z0F, nullptr, s_z, gz_w, gz_b,
        1.f/262144.f, 256, t1);
    gemm_bf16_m128<<<dim3(16,4,8),blk,0,stream>>>(wp_qkv, t1, qkvF, 512, 256, s_qkv);
    head_cov<<<512,blk,0,stream>>>(qkvF, s_qkv, gq_w, gq_b, covq, covk, sumq, sumk,
        Qbf, Kbf, Vbf, qnorm, kmaxu);
    attn_kernel<<<512,blk,0,stream>>>(Qbf, Kbf, Vbf, qnorm, kmaxu,
        covq, covk, sumq, sumk, z0F, s_attn);
    xform_bf16<<<dim3(16,4,8),blk,0,stream>>>(z0F, nullptr, s_attn, nullptr, nullptr,
        1.f/262144.f, 256, t0);
    gemm_bf16<<<dim3(16,4,8),blk,0,stream>>>(wp_out, t0, xF, 256, 256, s_x);
    xform_bf16<<<dim3(16,4,8),blk,0,stream>>>(xF, f, s_x, go_w, go_b,
        1.f/262144.f, 256, t1);
    gemm_bf16_m128<<<dim3(16,4,8),blk,0,stream>>>(wp_f1, t1, qkvF, 512, 256, s_h1);
    xform_bf16<<<dim3(16,8,8),blk,0,stream>>>(qkvF, nullptr, s_h1, g1_w, g1_b,
        1.f/524288.f, 512, t4);
    gemm_bf16<<<dim3(16,4,8),blk,0,stream>>>(wp_f2, t4, qkvF, 256, 512, s_h2);
    ew_final<<<2048,blk,0,stream>>>(f, xF, qkvF, s_x, s_h2,
        go_w, go_b, g2_w, g2_b, outp);
}